// Round 5
// baseline (431.910 us; speedup 1.0000x reference)
//
#include <hip/hip_runtime.h>
#include <hip/hip_bf16.h>
#include <stdint.h>

// MoE routed GEMM: out[i] = x[i] @ W[e_i] + b[e_i]
// B=8192, D=2048, E=8. fp32 in/out, bf16 MFMA compute.
// R8: the R4-R7 plateau (~140-180us) was GRID QUANTIZATION: 320 one-per-CU
// blocks on 256 CUs = 2 serial rounds => wall = 2 x T_block no matter the
// intra-block schedule. Fix: 128x128 tile, 512 thr = 8 waves of 64x32
// output (acc 32 VGPR/wave -> ~100 total, 4 waves/SIMD), LDS 32.5KB dbuf
// -> 4 blocks/CU co-resident (32 waves/CU). 1152 blocks ~ 1.1 fill rounds.
// Cross-block overlap (m114) replaces explicit pipelining: simple 2-phase
// prefetch loop (stage next -> ds_read+MFMA cur -> syncthreads). Swizzle
// pair (rule #21) kept, adapted to 4 slots -> conflict-free (measured 0).
// k_prep unchanged (control).

#define B_TOK 8192
#define DIM   2048
#define NEXP  8
#define BM 128
#define BN 128
#define BK 32

typedef __attribute__((ext_vector_type(4))) float f32x4;
typedef __attribute__((ext_vector_type(8))) short s16x8;

// RNE float->bf16
__device__ __forceinline__ uint32_t f2bf(float f) {
    uint32_t u = __float_as_uint(f);
    uint32_t r = u + 0x7fffu + ((u >> 16) & 1u);
    return r >> 16;
}

__device__ __forceinline__ void async16(const void* g, void* l) {
    __builtin_amdgcn_global_load_lds(
        (const __attribute__((address_space(1))) uint32_t*)g,
        (__attribute__((address_space(3))) uint32_t*)l, 16, 0, 0);
}

// ---- prep: block 0 = routing; blocks 1..8192 = x fp32->bf16 (unsorted);
// ---- blocks 8193..12288 = W[e][d][o] -> Wt[e][o][d] bf16 transpose.
__global__ __launch_bounds__(256) void k_prep(const float* __restrict__ x,
                                              const float* __restrict__ W,
                                              const int* __restrict__ idx,
                                              int* __restrict__ meta,
                                              int* __restrict__ perm,
                                              uint16_t* __restrict__ xb,
                                              uint16_t* __restrict__ Wt) {
    __shared__ __align__(16) char smem[16640];   // max(route 9252, wt 16640)
    int bid = blockIdx.x;
    int t = threadIdx.x;

    if (bid == 0) {
        // ---- routing: zero atomics, deterministic ----
        int (*cnt)[9] = (int(*)[9])smem;          // 256*9*4 = 9216
        int* offS = (int*)(smem + 9216);          // 9*4
        int myIdx[32];
        #pragma unroll
        for (int i = 0; i < 32; ++i) myIdx[i] = idx[t * 32 + i];
        int c[NEXP] = {0, 0, 0, 0, 0, 0, 0, 0};
        #pragma unroll
        for (int i = 0; i < 32; ++i) {
            int e = myIdx[i];
            #pragma unroll
            for (int k = 0; k < NEXP; ++k) c[k] += (e == k) ? 1 : 0;
        }
        #pragma unroll
        for (int k = 0; k < NEXP; ++k) cnt[t][k] = c[k];
        __syncthreads();
        if (t < NEXP) {                 // 8 threads: exclusive scan down column t
            int run = 0;
            for (int j = 0; j < 256; ++j) { int v = cnt[j][t]; cnt[j][t] = run; run += v; }
            offS[t] = run;
        }
        __syncthreads();
        if (t == 0) {
            int off = 0;
            #pragma unroll
            for (int e = 0; e < NEXP; ++e) {
                int v = offS[e];
                offS[e] = off; meta[16 + e] = off; off += v;
            }
            offS[NEXP] = off; meta[16 + NEXP] = off;
        }
        __syncthreads();
        int base[NEXP];
        #pragma unroll
        for (int k = 0; k < NEXP; ++k) base[k] = offS[k] + cnt[t][k];
        #pragma unroll
        for (int i = 0; i < 32; ++i) {
            int e = myIdx[i];
            int pos = 0;
            #pragma unroll
            for (int k = 0; k < NEXP; ++k) pos += (e == k) ? base[k] : 0;
            perm[pos] = t * 32 + i;
            #pragma unroll
            for (int k = 0; k < NEXP; ++k) base[k] += (e == k) ? 1 : 0;
        }
        return;
    }

    if (bid <= B_TOK) {
        // ---- x convert, original row order ----
        int p = bid - 1;
        const float4* xin = (const float4*)(x + (size_t)p * DIM);
        float4 a = xin[2 * t];
        float4 c = xin[2 * t + 1];
        uint4 o;
        o.x = f2bf(a.x) | (f2bf(a.y) << 16);
        o.y = f2bf(a.z) | (f2bf(a.w) << 16);
        o.z = f2bf(c.x) | (f2bf(c.y) << 16);
        o.w = f2bf(c.z) | (f2bf(c.w) << 16);
        *(uint4*)(xb + (size_t)p * DIM + t * 8) = o;
        return;
    }

    // ---- W transpose tile 128d x 64o ----
    int wb = bid - (B_TOK + 1);
    int bx = wb & 15, by = (wb >> 4) & 31, e = wb >> 9;
    int d0 = bx * 128, o0 = by * 64;
    uint32_t (*lds)[65] = (uint32_t(*)[65])smem;
    const float* Wp = W + ((size_t)e * DIM + d0) * DIM + o0;
    #pragma unroll
    for (int p = 0; p < 4; ++p) {
        int dp = p * 16 + (t >> 4);      // d-pair index 0..63
        int oc = (t & 15) * 4;           // o base
        const float* r0 = Wp + (size_t)(2 * dp) * DIM + oc;
        float4 v0 = *(const float4*)r0;
        float4 v1 = *(const float4*)(r0 + DIM);
        lds[oc + 0][dp ^ (((oc + 0) & 15) << 2)] = f2bf(v0.x) | (f2bf(v1.x) << 16);
        lds[oc + 1][dp ^ (((oc + 1) & 15) << 2)] = f2bf(v0.y) | (f2bf(v1.y) << 16);
        lds[oc + 2][dp ^ (((oc + 2) & 15) << 2)] = f2bf(v0.z) | (f2bf(v1.z) << 16);
        lds[oc + 3][dp ^ (((oc + 3) & 15) << 2)] = f2bf(v0.w) | (f2bf(v1.w) << 16);
    }
    __syncthreads();
    uint16_t* Wo = Wt + ((size_t)e * DIM + o0) * DIM + d0;
    #pragma unroll
    for (int q = 0; q < 4; ++q) {
        int o = q * 16 + (t >> 4);
        int cb = ((t & 15) * 4) ^ ((o & 15) << 2);
        uint4 w = *(const uint4*)&lds[o][cb];
        *(uint4*)(Wo + (size_t)o * DIM + (t & 15) * 8) = w;
    }
}

// ---- GEMM core: 128x128 tile, BK=32 dbuf, 8 waves x (64x32 out) ----------
// LDS [128 rows][32 elems]; read swizzle: phys 16B-slot = quad ^ (lr&3);
// stage pre-swizzles per-lane GLOBAL source slot (rule #21): thread t
// stages row t>>2, src slot (t&3)^((t>>2)&3) -> linear LDS dest t*16B.
// 2-phase: stage(next) -> ds_read+MFMA(cur) -> __syncthreads -> flip.
template<bool FULL>
__device__ __forceinline__ void gemm_core(
    uint16_t (*As)[BM * BK], uint16_t (*Bs)[BN * BK], int* permS,
    const uint16_t* __restrict__ xb, const uint16_t* __restrict__ Wt,
    const float* __restrict__ bias, const int* __restrict__ perm,
    float* __restrict__ out, int e, int m0, int valid, int n0) {

    int tid = threadIdx.x;
    if (tid < BM) permS[tid] = (tid < valid) ? perm[m0 + tid] : 0;

    int wave = tid >> 6, lane = tid & 63;
    int wm = (wave >> 2) * 64;       // 2 M-groups of 64 rows
    int wn = (wave & 3) * 32;        // 4 N-groups of 32 cols
    int lr = lane & 15, quad = lane >> 4;
    const int rdswz = (quad ^ (lr & 3)) * 8;   // element offset within row
    int nfw = 4;
    if (!FULL) { nfw = (valid > wm) ? ((valid - wm + 15) >> 4) : 0; if (nfw > 4) nfw = 4; }

    // staging sources: thread t -> row t>>2 (0..127), 16B slot t&3 (swz'd)
    const int srcswz = (((tid & 3) ^ ((tid >> 2) & 3)) * 8);
    int arow = m0 + (tid >> 2); if (arow > B_TOK - 1) arow = B_TOK - 1;
    const uint16_t* aSrc = xb + (size_t)perm[arow] * DIM + srcswz;
    const uint16_t* bSrc = Wt + ((size_t)e * DIM + n0 + (tid >> 2)) * DIM + srcswz;

    auto STAGE = [&](int buf, int k0) {
        async16(aSrc + k0, &As[buf][tid * 8]);
        async16(bSrc + k0, &Bs[buf][tid * 8]);
    };

    f32x4 acc[4][2] = {};

    STAGE(0, 0);
    __syncthreads();

    int cur = 0;
    for (int k0 = 0; k0 < DIM; k0 += BK) {
        if (k0 + BK < DIM) STAGE(cur ^ 1, k0 + BK);   // prefetch next tile
        s16x8 af[4], bf[2];
        #pragma unroll
        for (int ii = 0; ii < 4; ++ii)
            af[ii] = *(const s16x8*)&As[cur][(wm + ii * 16 + lr) * BK + rdswz];
        #pragma unroll
        for (int j = 0; j < 2; ++j)
            bf[j] = *(const s16x8*)&Bs[cur][(wn + j * 16 + lr) * BK + rdswz];
        #pragma unroll
        for (int ii = 0; ii < 4; ++ii) {
            if (FULL || ii < nfw) {
                #pragma unroll
                for (int j = 0; j < 2; ++j)
                    acc[ii][j] = __builtin_amdgcn_mfma_f32_16x16x32_bf16(
                        af[ii], bf[j], acc[ii][j], 0, 0, 0);
            }
        }
        __syncthreads();   // reads retired + staged tile landed
        cur ^= 1;
    }

    #pragma unroll
    for (int j = 0; j < 2; ++j) {
        int col = n0 + wn + j * 16 + lr;
        float bv = bias[e * DIM + col];
        #pragma unroll
        for (int ii = 0; ii < 4; ++ii) {
            #pragma unroll
            for (int r = 0; r < 4; ++r) {
                int lrow = wm + ii * 16 + quad * 4 + r;
                if (lrow < valid) {
                    out[(size_t)permS[lrow] * DIM + col] = acc[ii][j][r] + bv;
                }
            }
        }
    }
}

// ---- GEMM kernel: flat tile list, XCD-chunked bijective map --------------
// 1152 = 8 x 144 launched blocks >= worst-case tiles; extras return early.
__global__ __launch_bounds__(512, 4) void k_gemm(
    const uint16_t* __restrict__ xb, const uint16_t* __restrict__ Wt,
    const float* __restrict__ bias, const int* __restrict__ meta,
    const int* __restrict__ perm, float* __restrict__ out) {
    __shared__ uint16_t As[2][BM * BK];   // 2 x 8KB
    __shared__ uint16_t Bs[2][BN * BK];   // 2 x 8KB
    __shared__ int permS[BM];             // 512B

    int b = blockIdx.x;
    int g = (b & 7) * 144 + (b >> 3);     // XCD-chunked (1152 % 8 == 0)
    int yf = g >> 4, bx = g & 15;

    int e = -1, mloc = 0, cnt = 0, s0 = 0;
    int a = 0;
    #pragma unroll
    for (int i = 0; i < NEXP; ++i) {
        int ci = meta[17 + i] - meta[16 + i];
        int nfi = (ci + 127) >> 7;
        if (e < 0 && yf >= a && yf < a + nfi) {
            e = i; mloc = yf - a; cnt = ci; s0 = meta[16 + i];
        }
        a += nfi;
    }
    if (e < 0) return;                    // beyond last tile
    int m0 = s0 + mloc * BM;
    int valid = cnt - mloc * BM; if (valid > BM) valid = BM;
    int n0 = bx * BN;

    if (valid == BM)
        gemm_core<true >(As, Bs, permS, xb, Wt, bias, perm, out, e, m0, BM,    n0);
    else
        gemm_core<false>(As, Bs, permS, xb, Wt, bias, perm, out, e, m0, valid, n0);
}

// ---- launch --------------------------------------------------------------
// ws: [0,256) meta | [256,33024) perm | [64K, +33.55MB) xb | Wt 67.1MB.
extern "C" void kernel_launch(void* const* d_in, const int* in_sizes, int n_in,
                              void* d_out, int out_size, void* d_ws, size_t ws_size,
                              hipStream_t stream) {
    const float* x    = (const float*)d_in[0];
    const float* W    = (const float*)d_in[1];
    const float* bias = (const float*)d_in[2];
    const int*   idx  = (const int*)d_in[3];
    float* out = (float*)d_out;

    char* ws = (char*)d_ws;
    int* meta = (int*)ws;
    int* perm = (int*)(ws + 256);
    uint16_t* xb = (uint16_t*)(ws + 65536);
    uint16_t* Wt = (uint16_t*)(ws + 65536 + (size_t)B_TOK * DIM * 2);

    k_prep<<<1 + B_TOK + 4096, 256, 0, stream>>>(x, W, idx, meta, perm, xb, Wt);
    // worst-case tiles = (8192/128 + 8 partials) x 16 = 1152
    k_gemm<<<1152, 512, 0, stream>>>(xb, Wt, bias, meta, perm, out);
}

// Round 6
// 393.297 us; speedup vs baseline: 1.0982x; 1.0982x over previous
//
#include <hip/hip_runtime.h>
#include <hip/hip_bf16.h>
#include <stdint.h>

// MoE routed GEMM: out[i] = x[i] @ W[e_i] + b[e_i]
// B=8192, D=2048, E=8. fp32 in/out, bf16 MFMA compute.
// R9: R8 post-mortem found two quantified errors:
//  (1) swizzle slot=quad^(lr&3) is 4-way bank-conflicted (lr&1 is inside
//      lr&3; only 4 distinct bank groups) -> 1.33e7 conflict cycles.
//      Reverted to the R5-R7-verified family f(row)=(row>>1)&3: bank base
//      = lr&7 -> 8 groups x 2 lanes = conflict-free.
//  (2) 8 waves x (64x32) on a 128^2 tile reads 750 B/MFMA from LDS (af
//      reused 2x) -> LDS-BW-bound ~180us. Now 4 waves x (64x64): 500
//      B/MFMA, acc=64 f32/lane -> VGPR ~115 -> 4 blocks/CU co-resident
//      (16 waves/CU), cross-block overlap hides the 2-phase barrier.
// Grid 1152 x 256thr ~= 1.06 fill rounds of 1024 resident slots.
// k_prep unchanged (control).

#define B_TOK 8192
#define DIM   2048
#define NEXP  8
#define BM 128
#define BN 128
#define BK 32

typedef __attribute__((ext_vector_type(4))) float f32x4;
typedef __attribute__((ext_vector_type(8))) short s16x8;

// RNE float->bf16
__device__ __forceinline__ uint32_t f2bf(float f) {
    uint32_t u = __float_as_uint(f);
    uint32_t r = u + 0x7fffu + ((u >> 16) & 1u);
    return r >> 16;
}

__device__ __forceinline__ void async16(const void* g, void* l) {
    __builtin_amdgcn_global_load_lds(
        (const __attribute__((address_space(1))) uint32_t*)g,
        (__attribute__((address_space(3))) uint32_t*)l, 16, 0, 0);
}

// ---- prep: block 0 = routing; blocks 1..8192 = x fp32->bf16 (unsorted);
// ---- blocks 8193..12288 = W[e][d][o] -> Wt[e][o][d] bf16 transpose.
__global__ __launch_bounds__(256) void k_prep(const float* __restrict__ x,
                                              const float* __restrict__ W,
                                              const int* __restrict__ idx,
                                              int* __restrict__ meta,
                                              int* __restrict__ perm,
                                              uint16_t* __restrict__ xb,
                                              uint16_t* __restrict__ Wt) {
    __shared__ __align__(16) char smem[16640];   // max(route 9252, wt 16640)
    int bid = blockIdx.x;
    int t = threadIdx.x;

    if (bid == 0) {
        // ---- routing: zero atomics, deterministic ----
        int (*cnt)[9] = (int(*)[9])smem;          // 256*9*4 = 9216
        int* offS = (int*)(smem + 9216);          // 9*4
        int myIdx[32];
        #pragma unroll
        for (int i = 0; i < 32; ++i) myIdx[i] = idx[t * 32 + i];
        int c[NEXP] = {0, 0, 0, 0, 0, 0, 0, 0};
        #pragma unroll
        for (int i = 0; i < 32; ++i) {
            int e = myIdx[i];
            #pragma unroll
            for (int k = 0; k < NEXP; ++k) c[k] += (e == k) ? 1 : 0;
        }
        #pragma unroll
        for (int k = 0; k < NEXP; ++k) cnt[t][k] = c[k];
        __syncthreads();
        if (t < NEXP) {                 // 8 threads: exclusive scan down column t
            int run = 0;
            for (int j = 0; j < 256; ++j) { int v = cnt[j][t]; cnt[j][t] = run; run += v; }
            offS[t] = run;
        }
        __syncthreads();
        if (t == 0) {
            int off = 0;
            #pragma unroll
            for (int e = 0; e < NEXP; ++e) {
                int v = offS[e];
                offS[e] = off; meta[16 + e] = off; off += v;
            }
            offS[NEXP] = off; meta[16 + NEXP] = off;
        }
        __syncthreads();
        int base[NEXP];
        #pragma unroll
        for (int k = 0; k < NEXP; ++k) base[k] = offS[k] + cnt[t][k];
        #pragma unroll
        for (int i = 0; i < 32; ++i) {
            int e = myIdx[i];
            int pos = 0;
            #pragma unroll
            for (int k = 0; k < NEXP; ++k) pos += (e == k) ? base[k] : 0;
            perm[pos] = t * 32 + i;
            #pragma unroll
            for (int k = 0; k < NEXP; ++k) base[k] += (e == k) ? 1 : 0;
        }
        return;
    }

    if (bid <= B_TOK) {
        // ---- x convert, original row order ----
        int p = bid - 1;
        const float4* xin = (const float4*)(x + (size_t)p * DIM);
        float4 a = xin[2 * t];
        float4 c = xin[2 * t + 1];
        uint4 o;
        o.x = f2bf(a.x) | (f2bf(a.y) << 16);
        o.y = f2bf(a.z) | (f2bf(a.w) << 16);
        o.z = f2bf(c.x) | (f2bf(c.y) << 16);
        o.w = f2bf(c.z) | (f2bf(c.w) << 16);
        *(uint4*)(xb + (size_t)p * DIM + t * 8) = o;
        return;
    }

    // ---- W transpose tile 128d x 64o ----
    int wb = bid - (B_TOK + 1);
    int bx = wb & 15, by = (wb >> 4) & 31, e = wb >> 9;
    int d0 = bx * 128, o0 = by * 64;
    uint32_t (*lds)[65] = (uint32_t(*)[65])smem;
    const float* Wp = W + ((size_t)e * DIM + d0) * DIM + o0;
    #pragma unroll
    for (int p = 0; p < 4; ++p) {
        int dp = p * 16 + (t >> 4);      // d-pair index 0..63
        int oc = (t & 15) * 4;           // o base
        const float* r0 = Wp + (size_t)(2 * dp) * DIM + oc;
        float4 v0 = *(const float4*)r0;
        float4 v1 = *(const float4*)(r0 + DIM);
        lds[oc + 0][dp ^ (((oc + 0) & 15) << 2)] = f2bf(v0.x) | (f2bf(v1.x) << 16);
        lds[oc + 1][dp ^ (((oc + 1) & 15) << 2)] = f2bf(v0.y) | (f2bf(v1.y) << 16);
        lds[oc + 2][dp ^ (((oc + 2) & 15) << 2)] = f2bf(v0.z) | (f2bf(v1.z) << 16);
        lds[oc + 3][dp ^ (((oc + 3) & 15) << 2)] = f2bf(v0.w) | (f2bf(v1.w) << 16);
    }
    __syncthreads();
    uint16_t* Wo = Wt + ((size_t)e * DIM + o0) * DIM + d0;
    #pragma unroll
    for (int q = 0; q < 4; ++q) {
        int o = q * 16 + (t >> 4);
        int cb = ((t & 15) * 4) ^ ((o & 15) << 2);
        uint4 w = *(const uint4*)&lds[o][cb];
        *(uint4*)(Wo + (size_t)o * DIM + (t & 15) * 8) = w;
    }
}

// ---- GEMM core: 128x128 tile, BK=32 dbuf, 4 waves x (64x64 out) ----------
// LDS [128 rows][32 elems] per buffer (8KB A + 8KB B).
// Swizzle family f(row)=(row>>1)&3 (verified conflict-free R5-R7):
//   read : phys 16B-slot = quad ^ ((lr>>1)&3)   -> bank base = lr&7, 2-way
//   stage: chunk ch=c*256+tid -> row=ch>>2, dest slot ch&3 (linear LDS);
//          per-lane GLOBAL source slot = (ch&3)^((ch>>3)&3) (rule #21;
//          identical expression for c=0,1 since 256>>3=32 == 0 mod 4).
// 2-phase: stage(next) -> ds_read+MFMA(cur) -> __syncthreads -> flip.
template<bool FULL>
__device__ __forceinline__ void gemm_core(
    uint16_t (*As)[BM * BK], uint16_t (*Bs)[BN * BK], int* permS,
    const uint16_t* __restrict__ xb, const uint16_t* __restrict__ Wt,
    const float* __restrict__ bias, const int* __restrict__ perm,
    float* __restrict__ out, int e, int m0, int valid, int n0) {

    int tid = threadIdx.x;
    if (tid < BM) permS[tid] = (tid < valid) ? perm[m0 + tid] : 0;

    int wave = tid >> 6, lane = tid & 63;
    int wm = (wave >> 1) * 64;       // 2 M-groups of 64 rows
    int wn = (wave & 1) * 64;        // 2 N-groups of 64 cols
    int lr = lane & 15, quad = lane >> 4;
    const int rdswz = (quad ^ ((lr >> 1) & 3)) * 8;   // elem offset in row
    int nfw = 4;
    if (!FULL) { nfw = (valid > wm) ? ((valid - wm + 15) >> 4) : 0; if (nfw > 4) nfw = 4; }

    // staging sources: chunk ch = c*256+tid -> row ch>>2, src slot swz'd
    const int srcswz = (((tid & 3) ^ ((tid >> 3) & 3)) * 8);
    const uint16_t* aSrc[2];
    const uint16_t* bSrc[2];
    #pragma unroll
    for (int c = 0; c < 2; ++c) {
        int row = c * 64 + (tid >> 2);
        int ar = m0 + row; if (ar > B_TOK - 1) ar = B_TOK - 1;
        aSrc[c] = xb + (size_t)perm[ar] * DIM + srcswz;
        bSrc[c] = Wt + ((size_t)e * DIM + n0 + row) * DIM + srcswz;
    }

    auto STAGE = [&](int buf, int k0) {
        #pragma unroll
        for (int c = 0; c < 2; ++c) {
            async16(aSrc[c] + k0, &As[buf][(c * 256 + tid) * 8]);
            async16(bSrc[c] + k0, &Bs[buf][(c * 256 + tid) * 8]);
        }
    };

    f32x4 acc[4][4] = {};

    STAGE(0, 0);
    __syncthreads();

    int cur = 0;
    for (int k0 = 0; k0 < DIM; k0 += BK) {
        if (k0 + BK < DIM) STAGE(cur ^ 1, k0 + BK);   // prefetch next tile
        s16x8 af[4], bf[4];
        #pragma unroll
        for (int ii = 0; ii < 4; ++ii)
            af[ii] = *(const s16x8*)&As[cur][(wm + ii * 16 + lr) * BK + rdswz];
        #pragma unroll
        for (int j = 0; j < 4; ++j)
            bf[j] = *(const s16x8*)&Bs[cur][(wn + j * 16 + lr) * BK + rdswz];
        #pragma unroll
        for (int ii = 0; ii < 4; ++ii) {
            if (FULL || ii < nfw) {
                #pragma unroll
                for (int j = 0; j < 4; ++j)
                    acc[ii][j] = __builtin_amdgcn_mfma_f32_16x16x32_bf16(
                        af[ii], bf[j], acc[ii][j], 0, 0, 0);
            }
        }
        __syncthreads();   // reads retired + staged tile landed
        cur ^= 1;
    }

    #pragma unroll
    for (int j = 0; j < 4; ++j) {
        int col = n0 + wn + j * 16 + lr;
        float bv = bias[e * DIM + col];
        #pragma unroll
        for (int ii = 0; ii < 4; ++ii) {
            #pragma unroll
            for (int r = 0; r < 4; ++r) {
                int lrow = wm + ii * 16 + quad * 4 + r;
                if (lrow < valid) {
                    out[(size_t)permS[lrow] * DIM + col] = acc[ii][j][r] + bv;
                }
            }
        }
    }
}

// ---- GEMM kernel: flat tile list, XCD-chunked bijective map --------------
// 1152 = 8 x 144 launched blocks >= worst-case tiles (72 M-slots x 16 N);
// extras return early.
__global__ __launch_bounds__(256, 4) void k_gemm(
    const uint16_t* __restrict__ xb, const uint16_t* __restrict__ Wt,
    const float* __restrict__ bias, const int* __restrict__ meta,
    const int* __restrict__ perm, float* __restrict__ out) {
    __shared__ uint16_t As[2][BM * BK];   // 2 x 8KB
    __shared__ uint16_t Bs[2][BN * BK];   // 2 x 8KB
    __shared__ int permS[BM];             // 512B

    int b = blockIdx.x;
    int g = (b & 7) * 144 + (b >> 3);     // XCD-chunked (1152 % 8 == 0)
    int yf = g >> 4, bx = g & 15;

    int e = -1, mloc = 0, cnt = 0, s0 = 0;
    int a = 0;
    #pragma unroll
    for (int i = 0; i < NEXP; ++i) {
        int ci = meta[17 + i] - meta[16 + i];
        int nfi = (ci + 127) >> 7;
        if (e < 0 && yf >= a && yf < a + nfi) {
            e = i; mloc = yf - a; cnt = ci; s0 = meta[16 + i];
        }
        a += nfi;
    }
    if (e < 0) return;                    // beyond last tile
    int m0 = s0 + mloc * BM;
    int valid = cnt - mloc * BM; if (valid > BM) valid = BM;
    int n0 = bx * BN;

    if (valid == BM)
        gemm_core<true >(As, Bs, permS, xb, Wt, bias, perm, out, e, m0, BM,    n0);
    else
        gemm_core<false>(As, Bs, permS, xb, Wt, bias, perm, out, e, m0, valid, n0);
}

// ---- launch --------------------------------------------------------------
// ws: [0,256) meta | [256,33024) perm | [64K, +33.55MB) xb | Wt 67.1MB.
extern "C" void kernel_launch(void* const* d_in, const int* in_sizes, int n_in,
                              void* d_out, int out_size, void* d_ws, size_t ws_size,
                              hipStream_t stream) {
    const float* x    = (const float*)d_in[0];
    const float* W    = (const float*)d_in[1];
    const float* bias = (const float*)d_in[2];
    const int*   idx  = (const int*)d_in[3];
    float* out = (float*)d_out;

    char* ws = (char*)d_ws;
    int* meta = (int*)ws;
    int* perm = (int*)(ws + 256);
    uint16_t* xb = (uint16_t*)(ws + 65536);
    uint16_t* Wt = (uint16_t*)(ws + 65536 + (size_t)B_TOK * DIM * 2);

    k_prep<<<1 + B_TOK + 4096, 256, 0, stream>>>(x, W, idx, meta, perm, xb, Wt);
    // worst-case tiles = (8192/128 + 8 partials) x 16 = 1152
    k_gemm<<<1152, 256, 0, stream>>>(xb, Wt, bias, meta, perm, out);
}